// Round 18
// baseline (150.195 us; speedup 1.0000x reference)
//
#include <hip/hip_runtime.h>

typedef unsigned short u16;
typedef unsigned int   u32;

typedef __bf16 bf16x8 __attribute__((ext_vector_type(8)));
typedef float  f32x4  __attribute__((ext_vector_type(4)));

typedef const __attribute__((address_space(1))) void* gas_ptr;
typedef __attribute__((address_space(3))) void* las_ptr;

__device__ __forceinline__ u16 f2bf(float f) {
  u32 u = __builtin_bit_cast(u32, f);
  u += 0x7fffu + ((u >> 16) & 1u);
  return (u16)(u >> 16);
}
__device__ __forceinline__ float bf2f(u16 u) {
  return __builtin_bit_cast(float, ((u32)u) << 16);
}
// packed f32->bf16x2 hardware convert (RTNE), 1 VALU op per pair
__device__ __forceinline__ u32 cvtpk(float a, float b) {
  u32 r;
  asm("v_cvt_pk_bf16_f32 %0, %1, %2" : "=v"(r) : "v"(a), "v"(b));
  return r;
}
// raw v_exp_f32 (2^x, ~1ulp)
__device__ __forceinline__ float fexp2(float x) {
  return __builtin_amdgcn_exp2f(x);
}

// ---------------------------------------------------------------------------
// Kernel 1: BatchNorm over F-channels (stats over B,E) + bf16 cast.
// ---------------------------------------------------------------------------
__global__ __launch_bounds__(256) void bn_norm_kernel(
    const float* __restrict__ x, const float* __restrict__ gamma,
    const float* __restrict__ beta, u16* __restrict__ xn) {
  const int F = 1024, E = 1024;
  int f = blockIdx.x;
  __shared__ float sh[8192];
  __shared__ float ps[4], pq[4], sc[2];

  const float* xf = x + (size_t)f * E;
  float ls = 0.f, lq = 0.f;
  for (int i = threadIdx.x; i < 8192; i += 256) {
    int b = i >> 10, e = i & 1023;
    float v = xf[(size_t)b * F * E + e];
    sh[i] = v;
    ls += v;
    lq += v * v;
  }
  #pragma unroll
  for (int o = 32; o > 0; o >>= 1) {
    ls += __shfl_down(ls, o, 64);
    lq += __shfl_down(lq, o, 64);
  }
  int w = threadIdx.x >> 6;
  if ((threadIdx.x & 63) == 0) { ps[w] = ls; pq[w] = lq; }
  __syncthreads();
  if (threadIdx.x == 0) {
    float s = ps[0] + ps[1] + ps[2] + ps[3];
    float q = pq[0] + pq[1] + pq[2] + pq[3];
    float mean = s * (1.f / 8192.f);
    float var = q * (1.f / 8192.f) - mean * mean;
    float scale = gamma[f] * rsqrtf(var + 1e-5f);
    sc[0] = scale;
    sc[1] = beta[f] - mean * scale;
  }
  __syncthreads();
  float scale = sc[0], shift = sc[1];
  for (int i = threadIdx.x; i < 8192; i += 256) {
    int b = i >> 10, e = i & 1023;
    xn[((size_t)(b * F + f)) * E + e] = f2bf(sh[i] * scale + shift);
  }
}

// ---------------------------------------------------------------------------
// Kernel 2: W_qkv f32 -> bf16
// ---------------------------------------------------------------------------
__global__ __launch_bounds__(256) void wconv_kernel(
    const float* __restrict__ W, u16* __restrict__ Wb) {
  const int total = 3072 * 1024 / 4;
  for (int i = blockIdx.x * 256 + threadIdx.x; i < total; i += gridDim.x * 256) {
    float4 v = ((const float4*)W)[i];
    ushort4 o;
    o.x = f2bf(v.x); o.y = f2bf(v.y); o.z = f2bf(v.z); o.w = f2bf(v.w);
    ((ushort4*)Wb)[i] = o;
  }
}

// ---------------------------------------------------------------------------
// Kernel 3: GEMM (m97 structure + R15 swizzle) with FUSED V-transpose epilogue
// (R16-verified). Q/K cols -> qkv; V cols -> Vt with baked key permutation.
// ---------------------------------------------------------------------------
__global__ __launch_bounds__(256) void gemm_qkv_kernel(
    const u16* __restrict__ A, const u16* __restrict__ Bw,
    const float* __restrict__ bias, u16* __restrict__ C,
    u16* __restrict__ Vt) {
  const int K = 1024, N = 3072;
  __shared__ u16 As[128 * 32];
  __shared__ u16 Bs[128 * 32];

  int m0 = blockIdx.x * 128, n0 = blockIdx.y * 128;
  int t = threadIdx.x, lane = t & 63, w = t >> 6;
  int wr = w >> 1, wc = w & 1;
  int r = lane & 15, g = lane >> 4;

  int srow = t >> 2;
  int scol = ((t & 3) ^ ((srow >> 1) & 3)) * 8;   // pre-swizzled source chunk
  const u16* gA  = A  + (size_t)(m0 + srow) * K + scol;
  const u16* gA2 = A  + (size_t)(m0 + 64 + srow) * K + scol;
  const u16* gB  = Bw + (size_t)(n0 + srow) * K + scol;
  const u16* gB2 = Bw + (size_t)(n0 + 64 + srow) * K + scol;
  u16* lA  = As + t * 8;
  u16* lA2 = As + 2048 + t * 8;
  u16* lB  = Bs + t * 8;
  u16* lB2 = Bs + 2048 + t * 8;

  f32x4 acc[4][4] = {};

  int rc = (g ^ ((r >> 1) & 3)) * 8;
  const u16* pA = As + (size_t)(wr * 64 + r) * 32 + rc;
  const u16* pB = Bs + (size_t)(wc * 64 + r) * 32 + rc;

  for (int k0 = 0; k0 < K; k0 += 32) {
    __builtin_amdgcn_global_load_lds((gas_ptr)gA,  (las_ptr)lA,  16, 0, 0);
    __builtin_amdgcn_global_load_lds((gas_ptr)gA2, (las_ptr)lA2, 16, 0, 0);
    __builtin_amdgcn_global_load_lds((gas_ptr)gB,  (las_ptr)lB,  16, 0, 0);
    __builtin_amdgcn_global_load_lds((gas_ptr)gB2, (las_ptr)lB2, 16, 0, 0);
    gA += 32; gA2 += 32; gB += 32; gB2 += 32;
    __syncthreads();

    bf16x8 af[4], bfr[4];
    #pragma unroll
    for (int mi = 0; mi < 4; ++mi)
      af[mi] = __builtin_bit_cast(bf16x8, *(const int4*)(pA + mi * 512));
    #pragma unroll
    for (int ni = 0; ni < 4; ++ni)
      bfr[ni] = __builtin_bit_cast(bf16x8, *(const int4*)(pB + ni * 512));
    #pragma unroll
    for (int mi = 0; mi < 4; ++mi)
      #pragma unroll
      for (int ni = 0; ni < 4; ++ni)
        acc[mi][ni] = __builtin_amdgcn_mfma_f32_16x16x32_bf16(af[mi], bfr[ni], acc[mi][ni], 0, 0, 0);
    __syncthreads();
  }

  // ---- epilogue: Q/K -> qkv ; V -> Vt (baked permutation)
  int b_ = m0 >> 10;
  #pragma unroll
  for (int ni = 0; ni < 4; ++ni) {
    int colb = n0 + wc * 64 + ni * 16;        // wave-uniform fragment base
    int col = colb + r;
    float bv = bias[col];
    int h_ = colb / 192;
    int rr = colb - h_ * 192;
    if (rr >= 128) {
      int d_ = rr - 128 + r;
      u16* vtd = Vt + (size_t)(b_ * 16 + h_) * 65536 + (size_t)d_ * 1024;
      #pragma unroll
      for (int mi = 0; mi < 4; ++mi) {
        int fbase = (m0 & 1023) + wr * 64 + mi * 16 + g * 4;
        int pos = (fbase & ~31) + ((g >> 1) * 16) + ((g & 1) * 8) + ((mi & 1) * 4);
        uint2 st;
        st.x = cvtpk(acc[mi][ni][0] + bv, acc[mi][ni][1] + bv);
        st.y = cvtpk(acc[mi][ni][2] + bv, acc[mi][ni][3] + bv);
        *(uint2*)(vtd + pos) = st;
      }
    } else {
      #pragma unroll
      for (int mi = 0; mi < 4; ++mi) {
        int row = m0 + wr * 64 + mi * 16 + g * 4;
        #pragma unroll
        for (int j = 0; j < 4; ++j)
          C[(size_t)(row + j) * N + col] = f2bf(acc[mi][ni][j] + bv);
      }
    }
  }
}

// ---------------------------------------------------------------------------
// Kernel 4: flash attention v10 — KVBLK=128, double-buffered (64KB LDS),
// lsum via ones-column MFMA (no psum tree, no epilogue shuffles).
//  - K tile: 128 rows x 64 cols, chunk^(row&7) swizzle (unchanged pattern).
//  - V tile: 64 d-rows x 128 cols, chunk^(row&15) swizzle, read chunk^(q).
//  - 8 tiles: half the barriers/waits/stage-addressing of v9.
//  - seeded-C softmax, fexp2, cvt_pk, defer-max, setprio as before.
// ---------------------------------------------------------------------------
__global__ __launch_bounds__(256) void attn_kernel(
    const u16* __restrict__ qkv, const u16* __restrict__ Vt,
    float* __restrict__ out) {
  const int F = 1024, NQ = 3072;
  int bid = blockIdx.x;           // 2048 blocks
  int xcd = bid & 7;
  int li  = bid >> 3;             // 0..255
  int bh  = ((li >> 4) << 3) | xcd;
  int ql  = li & 15;
  int w   = threadIdx.x >> 6;
  int lane = threadIdx.x & 63;
  int q = lane & 15, g = lane >> 4;
  int qs = q & 7;
  int q0 = ql * 64 + w * 16;
  int b = bh >> 4, h = bh & 15;

  const u16* base = qkv + (size_t)b * F * NQ + h * 192;
  const u16* VtBH = Vt + (size_t)bh * 65536;

  // K bufs: 2 x 8192 u16 @0 ; V bufs: 2 x 8192 u16 @16384  (64 KB total)
  __shared__ u16 S[32768];

  int i8 = lane >> 3;
  int ic = lane & 7;

  const float qscale = 0.125f * 1.4426950408889634f;
  bf16x8 Qf0, Qf1;
  {
    const u16* qp = base + (size_t)(q0 + q) * NQ + g * 8;
    union { int4 v; u16 u[8]; } uu0, uu1;
    uu0.v = *(const int4*)(qp);
    uu1.v = *(const int4*)(qp + 32);
    union { u32 w4[4]; bf16x8 v; } p0, p1;
    #pragma unroll
    for (int j = 0; j < 4; ++j) {
      p0.w4[j] = cvtpk(bf2f(uu0.u[2 * j]) * qscale, bf2f(uu0.u[2 * j + 1]) * qscale);
      p1.w4[j] = cvtpk(bf2f(uu1.u[2 * j]) * qscale, bf2f(uu1.u[2 * j + 1]) * qscale);
    }
    Qf0 = p0.v; Qf1 = p1.v;
  }

  // ones A-fragment for the lsum MFMA
  union { u16 u[8]; bf16x8 v; } ones_;
  #pragma unroll
  for (int j = 0; j < 8; ++j) ones_.u[j] = 0x3F80;
  const bf16x8 Ones = ones_.v;

  f32x4 acc[4] = {};
  f32x4 accS = {};                 // every lane accumulates full lsum(q)
  float m = 0.0f;

  // stage one 128-key tile (K: 128x64, V: 64x128) into buffer buf
  #define STAGE(buf, kt)                                                       \
    do {                                                                       \
      int kb_ = (kt) * 128;                                                    \
      _Pragma("unroll")                                                        \
      for (int rr = 0; rr < 4; ++rr) {                                         \
        int r_ = rr * 32 + w * 8 + i8;                                         \
        int sc_ = (ic ^ (r_ & 7)) * 8;                                         \
        const u16* ks_ = base + (size_t)(kb_ + r_) * NQ + 64 + sc_;            \
        __builtin_amdgcn_global_load_lds((gas_ptr)ks_,                         \
            (las_ptr)&S[(buf) * 8192 + (rr * 32 + w * 8) * 64], 16, 0, 0);     \
      }                                                                        \
      _Pragma("unroll")                                                        \
      for (int jj = 0; jj < 4; ++jj) {                                         \
        int slot = jj * 256 + w * 64 + lane;                                   \
        int vr_ = slot >> 4;                                                   \
        int vc_ = slot & 15;                                                   \
        int sc_ = (vc_ ^ (vr_ & 15)) * 8;                                      \
        const u16* vs_ = VtBH + (size_t)vr_ * 1024 + kb_ + sc_;                \
        __builtin_amdgcn_global_load_lds((gas_ptr)vs_,                         \
            (las_ptr)&S[16384 + (buf) * 8192 + (jj * 256 + w * 64) * 8], 16, 0, 0);\
      }                                                                        \
    } while (0)

  STAGE(0, 0);
  asm volatile("s_waitcnt vmcnt(0)" ::: "memory");
  __builtin_amdgcn_s_barrier();
  __builtin_amdgcn_sched_barrier(0);

  #pragma unroll
  for (int kt = 0; kt < 8; ++kt) {
    const int cur = kt & 1;
    if (kt < 7) STAGE(cur ^ 1, kt + 1);

    const u16* Kb = &S[cur * 8192];
    const u16* Vb = &S[16384 + cur * 8192];

    // ---- QK^T: 8 key-groups of 16, C seeded with -m
    f32x4 s[8];
    f32x4 seed = {-m, -m, -m, -m};
    __builtin_amdgcn_s_setprio(1);
    #pragma unroll
    for (int ks = 0; ks < 8; ++ks) {
      int row = ks * 16 + q;
      int4 k0 = *(const int4*)&Kb[row * 64 + ((g ^ qs) * 8)];
      int4 k1 = *(const int4*)&Kb[row * 64 + (((4 + g) ^ qs) * 8)];
      f32x4 sv = seed;
      sv = __builtin_amdgcn_mfma_f32_16x16x32_bf16(__builtin_bit_cast(bf16x8, k0), Qf0, sv, 0, 0, 0);
      sv = __builtin_amdgcn_mfma_f32_16x16x32_bf16(__builtin_bit_cast(bf16x8, k1), Qf1, sv, 0, 0, 0);
      s[ks] = sv;
    }
    __builtin_amdgcn_s_setprio(0);

    // ---- balanced max over 32 per-lane scores
    float mk[8];
    #pragma unroll
    for (int ks = 0; ks < 8; ++ks)
      mk[ks] = fmaxf(fmaxf(s[ks][0], s[ks][1]), fmaxf(s[ks][2], s[ks][3]));
    float tmx = fmaxf(fmaxf(fmaxf(mk[0], mk[1]), fmaxf(mk[2], mk[3])),
                      fmaxf(fmaxf(mk[4], mk[5]), fmaxf(mk[6], mk[7])));

    float p[32];
    if (__builtin_expect(__any(tmx > 8.0f), 0)) {
      float tr = fmaxf(tmx, __shfl_xor(tmx, 16, 64));
      tr = fmaxf(tr, __shfl_xor(tr, 32, 64));
      float dm = fmaxf(tr, 0.f);
      float alpha = fexp2(-dm);
      acc[0] *= alpha; acc[1] *= alpha; acc[2] *= alpha; acc[3] *= alpha;
      accS *= alpha;
      m += dm;
      #pragma unroll
      for (int ks = 0; ks < 8; ++ks) {
        p[ks * 4 + 0] = fexp2(s[ks][0] - dm);
        p[ks * 4 + 1] = fexp2(s[ks][1] - dm);
        p[ks * 4 + 2] = fexp2(s[ks][2] - dm);
        p[ks * 4 + 3] = fexp2(s[ks][3] - dm);
      }
    } else {
      #pragma unroll
      for (int ks = 0; ks < 8; ++ks) {
        p[ks * 4 + 0] = fexp2(s[ks][0]);
        p[ks * 4 + 1] = fexp2(s[ks][1]);
        p[ks * 4 + 2] = fexp2(s[ks][2]);
        p[ks * 4 + 3] = fexp2(s[ks][3]);
      }
    }

    // ---- pack 4 PV B-frags (keys pre-permuted per 32-block in Vt)
    union { u32 w4[4]; bf16x8 v; } pb[4];
    #pragma unroll
    for (int cc = 0; cc < 4; ++cc) {
      pb[cc].w4[0] = cvtpk(p[cc * 8 + 0], p[cc * 8 + 1]);
      pb[cc].w4[1] = cvtpk(p[cc * 8 + 2], p[cc * 8 + 3]);
      pb[cc].w4[2] = cvtpk(p[cc * 8 + 4], p[cc * 8 + 5]);
      pb[cc].w4[3] = cvtpk(p[cc * 8 + 6], p[cc * 8 + 7]);
    }

    // ---- PV (16 MFMA) + lsum via ones-MFMA (4 MFMA)
    __builtin_amdgcn_s_setprio(1);
    #pragma unroll
    for (int dt = 0; dt < 4; ++dt) {
      int row = dt * 16 + q;
      #pragma unroll
      for (int cc = 0; cc < 4; ++cc) {
        int4 vv = *(const int4*)&Vb[row * 128 + (((cc * 4 + g) ^ q) * 8)];
        acc[dt] = __builtin_amdgcn_mfma_f32_16x16x32_bf16(
            __builtin_bit_cast(bf16x8, vv), pb[cc].v, acc[dt], 0, 0, 0);
      }
    }
    #pragma unroll
    for (int cc = 0; cc < 4; ++cc)
      accS = __builtin_amdgcn_mfma_f32_16x16x32_bf16(Ones, pb[cc].v, accS, 0, 0, 0);
    __builtin_amdgcn_s_setprio(0);

    asm volatile("s_waitcnt vmcnt(0)" ::: "memory");
    __builtin_amdgcn_s_barrier();
    __builtin_amdgcn_sched_barrier(0);
  }
  #undef STAGE

  // ---- epilogue: lsum complete in every lane (accS rows identical)
  float inv = 1.0f / accS[0];

  float* oT = (float*)S + (size_t)w * 1088;
  #pragma unroll
  for (int dt = 0; dt < 4; ++dt) {
    oT[(dt * 16 + g * 4 + 0) * 17 + q] = acc[dt][0] * inv;
    oT[(dt * 16 + g * 4 + 1) * 17 + q] = acc[dt][1] * inv;
    oT[(dt * 16 + g * 4 + 2) * 17 + q] = acc[dt][2] * inv;
    oT[(dt * 16 + g * 4 + 3) * 17 + q] = acc[dt][3] * inv;
  }
  asm volatile("s_waitcnt lgkmcnt(0)" ::: "memory");
  int oq = lane >> 2, dc = (lane & 3) * 16;
  float* orow = out + (size_t)(b * F + q0 + oq) * 1024 + h * 64 + dc;
  #pragma unroll
  for (int c4 = 0; c4 < 4; ++c4) {
    float4 v;
    v.x = oT[(dc + c4 * 4 + 0) * 17 + oq];
    v.y = oT[(dc + c4 * 4 + 1) * 17 + oq];
    v.z = oT[(dc + c4 * 4 + 2) * 17 + oq];
    v.w = oT[(dc + c4 * 4 + 3) * 17 + oq];
    *(float4*)(orow + c4 * 4) = v;
  }
}

// ---------------------------------------------------------------------------
extern "C" void kernel_launch(void* const* d_in, const int* in_sizes, int n_in,
                              void* d_out, int out_size, void* d_ws, size_t ws_size,
                              hipStream_t stream) {
  const float* x     = (const float*)d_in[0];
  const float* gamma = (const float*)d_in[1];
  const float* beta  = (const float*)d_in[2];
  const float* W     = (const float*)d_in[3];
  const float* bias  = (const float*)d_in[4];
  float* out = (float*)d_out;

  char* ws = (char*)d_ws;
  u16* xn  = (u16*)ws;                                   // 16 MB
  u16* Wb  = (u16*)(ws + (size_t)16 * 1024 * 1024);      //  6 MB
  u16* qkv = (u16*)(ws + (size_t)22 * 1024 * 1024);      // 48 MB
  u16* Vt  = (u16*)(ws + (size_t)70 * 1024 * 1024);      // 16 MB

  bn_norm_kernel<<<1024, 256, 0, stream>>>(x, gamma, beta, xn);
  wconv_kernel<<<768, 256, 0, stream>>>(W, Wb);
  gemm_qkv_kernel<<<dim3(64, 24), 256, 0, stream>>>(xn, Wb, bias, qkv, Vt);
  attn_kernel<<<2048, 256, 0, stream>>>(qkv, Vt, out);
}

// Round 19
// 144.027 us; speedup vs baseline: 1.0428x; 1.0428x over previous
//
#include <hip/hip_runtime.h>

typedef unsigned short u16;
typedef unsigned int   u32;

typedef __bf16 bf16x8 __attribute__((ext_vector_type(8)));
typedef float  f32x4  __attribute__((ext_vector_type(4)));

typedef const __attribute__((address_space(1))) void* gas_ptr;
typedef __attribute__((address_space(3))) void* las_ptr;

__device__ __forceinline__ u16 f2bf(float f) {
  u32 u = __builtin_bit_cast(u32, f);
  u += 0x7fffu + ((u >> 16) & 1u);
  return (u16)(u >> 16);
}
__device__ __forceinline__ float bf2f(u16 u) {
  return __builtin_bit_cast(float, ((u32)u) << 16);
}
// packed f32->bf16x2 hardware convert (RTNE), 1 VALU op per pair
__device__ __forceinline__ u32 cvtpk(float a, float b) {
  u32 r;
  asm("v_cvt_pk_bf16_f32 %0, %1, %2" : "=v"(r) : "v"(a), "v"(b));
  return r;
}
// raw v_exp_f32 (2^x, ~1ulp)
__device__ __forceinline__ float fexp2(float x) {
  return __builtin_amdgcn_exp2f(x);
}

// ---------------------------------------------------------------------------
// Kernel 1: BatchNorm over F-channels (stats over B,E) + bf16 cast.
// ---------------------------------------------------------------------------
__global__ __launch_bounds__(256) void bn_norm_kernel(
    const float* __restrict__ x, const float* __restrict__ gamma,
    const float* __restrict__ beta, u16* __restrict__ xn) {
  const int F = 1024, E = 1024;
  int f = blockIdx.x;
  __shared__ float sh[8192];
  __shared__ float ps[4], pq[4], sc[2];

  const float* xf = x + (size_t)f * E;
  float ls = 0.f, lq = 0.f;
  for (int i = threadIdx.x; i < 8192; i += 256) {
    int b = i >> 10, e = i & 1023;
    float v = xf[(size_t)b * F * E + e];
    sh[i] = v;
    ls += v;
    lq += v * v;
  }
  #pragma unroll
  for (int o = 32; o > 0; o >>= 1) {
    ls += __shfl_down(ls, o, 64);
    lq += __shfl_down(lq, o, 64);
  }
  int w = threadIdx.x >> 6;
  if ((threadIdx.x & 63) == 0) { ps[w] = ls; pq[w] = lq; }
  __syncthreads();
  if (threadIdx.x == 0) {
    float s = ps[0] + ps[1] + ps[2] + ps[3];
    float q = pq[0] + pq[1] + pq[2] + pq[3];
    float mean = s * (1.f / 8192.f);
    float var = q * (1.f / 8192.f) - mean * mean;
    float scale = gamma[f] * rsqrtf(var + 1e-5f);
    sc[0] = scale;
    sc[1] = beta[f] - mean * scale;
  }
  __syncthreads();
  float scale = sc[0], shift = sc[1];
  for (int i = threadIdx.x; i < 8192; i += 256) {
    int b = i >> 10, e = i & 1023;
    xn[((size_t)(b * F + f)) * E + e] = f2bf(sh[i] * scale + shift);
  }
}

// ---------------------------------------------------------------------------
// Kernel 2: W_qkv f32 -> bf16
// ---------------------------------------------------------------------------
__global__ __launch_bounds__(256) void wconv_kernel(
    const float* __restrict__ W, u16* __restrict__ Wb) {
  const int total = 3072 * 1024 / 4;
  for (int i = blockIdx.x * 256 + threadIdx.x; i < total; i += gridDim.x * 256) {
    float4 v = ((const float4*)W)[i];
    ushort4 o;
    o.x = f2bf(v.x); o.y = f2bf(v.y); o.z = f2bf(v.z); o.w = f2bf(v.w);
    ((ushort4*)Wb)[i] = o;
  }
}

// ---------------------------------------------------------------------------
// Kernel 3: GEMM (m97 structure + R15 swizzle) with FUSED V-transpose epilogue
// (R16-verified). Q/K cols -> qkv; V cols -> Vt with baked key permutation.
// ---------------------------------------------------------------------------
__global__ __launch_bounds__(256) void gemm_qkv_kernel(
    const u16* __restrict__ A, const u16* __restrict__ Bw,
    const float* __restrict__ bias, u16* __restrict__ C,
    u16* __restrict__ Vt) {
  const int K = 1024, N = 3072;
  __shared__ u16 As[128 * 32];
  __shared__ u16 Bs[128 * 32];

  int m0 = blockIdx.x * 128, n0 = blockIdx.y * 128;
  int t = threadIdx.x, lane = t & 63, w = t >> 6;
  int wr = w >> 1, wc = w & 1;
  int r = lane & 15, g = lane >> 4;

  int srow = t >> 2;
  int scol = ((t & 3) ^ ((srow >> 1) & 3)) * 8;   // pre-swizzled source chunk
  const u16* gA  = A  + (size_t)(m0 + srow) * K + scol;
  const u16* gA2 = A  + (size_t)(m0 + 64 + srow) * K + scol;
  const u16* gB  = Bw + (size_t)(n0 + srow) * K + scol;
  const u16* gB2 = Bw + (size_t)(n0 + 64 + srow) * K + scol;
  u16* lA  = As + t * 8;
  u16* lA2 = As + 2048 + t * 8;
  u16* lB  = Bs + t * 8;
  u16* lB2 = Bs + 2048 + t * 8;

  f32x4 acc[4][4] = {};

  int rc = (g ^ ((r >> 1) & 3)) * 8;
  const u16* pA = As + (size_t)(wr * 64 + r) * 32 + rc;
  const u16* pB = Bs + (size_t)(wc * 64 + r) * 32 + rc;

  for (int k0 = 0; k0 < K; k0 += 32) {
    __builtin_amdgcn_global_load_lds((gas_ptr)gA,  (las_ptr)lA,  16, 0, 0);
    __builtin_amdgcn_global_load_lds((gas_ptr)gA2, (las_ptr)lA2, 16, 0, 0);
    __builtin_amdgcn_global_load_lds((gas_ptr)gB,  (las_ptr)lB,  16, 0, 0);
    __builtin_amdgcn_global_load_lds((gas_ptr)gB2, (las_ptr)lB2, 16, 0, 0);
    gA += 32; gA2 += 32; gB += 32; gB2 += 32;
    __syncthreads();

    bf16x8 af[4], bfr[4];
    #pragma unroll
    for (int mi = 0; mi < 4; ++mi)
      af[mi] = __builtin_bit_cast(bf16x8, *(const int4*)(pA + mi * 512));
    #pragma unroll
    for (int ni = 0; ni < 4; ++ni)
      bfr[ni] = __builtin_bit_cast(bf16x8, *(const int4*)(pB + ni * 512));
    #pragma unroll
    for (int mi = 0; mi < 4; ++mi)
      #pragma unroll
      for (int ni = 0; ni < 4; ++ni)
        acc[mi][ni] = __builtin_amdgcn_mfma_f32_16x16x32_bf16(af[mi], bfr[ni], acc[mi][ni], 0, 0, 0);
    __syncthreads();
  }

  // ---- epilogue: Q/K -> qkv ; V -> Vt (baked permutation)
  int b_ = m0 >> 10;
  #pragma unroll
  for (int ni = 0; ni < 4; ++ni) {
    int colb = n0 + wc * 64 + ni * 16;        // wave-uniform fragment base
    int col = colb + r;
    float bv = bias[col];
    int h_ = colb / 192;
    int rr = colb - h_ * 192;
    if (rr >= 128) {
      int d_ = rr - 128 + r;
      u16* vtd = Vt + (size_t)(b_ * 16 + h_) * 65536 + (size_t)d_ * 1024;
      #pragma unroll
      for (int mi = 0; mi < 4; ++mi) {
        int fbase = (m0 & 1023) + wr * 64 + mi * 16 + g * 4;
        int pos = (fbase & ~31) + ((g >> 1) * 16) + ((g & 1) * 8) + ((mi & 1) * 4);
        uint2 st;
        st.x = cvtpk(acc[mi][ni][0] + bv, acc[mi][ni][1] + bv);
        st.y = cvtpk(acc[mi][ni][2] + bv, acc[mi][ni][3] + bv);
        *(uint2*)(vtd + pos) = st;
      }
    } else {
      #pragma unroll
      for (int mi = 0; mi < 4; ++mi) {
        int row = m0 + wr * 64 + mi * 16 + g * 4;
        #pragma unroll
        for (int j = 0; j < 4; ++j)
          C[(size_t)(row + j) * N + col] = f2bf(acc[mi][ni][j] + bv);
      }
    }
  }
}

// ---------------------------------------------------------------------------
// Kernel 4: flash attention v11 — v9 (KVBLK=64, triple-buffer, counted vmcnt)
// + lsum via ones-column MFMA (psum tree & epilogue shuffles deleted).
// ---------------------------------------------------------------------------
__global__ __launch_bounds__(256) void attn_kernel(
    const u16* __restrict__ qkv, const u16* __restrict__ Vt,
    float* __restrict__ out) {
  const int F = 1024, NQ = 3072;
  int bid = blockIdx.x;           // 2048 blocks
  int xcd = bid & 7;
  int li  = bid >> 3;             // 0..255
  int bh  = ((li >> 4) << 3) | xcd;
  int ql  = li & 15;
  int w   = threadIdx.x >> 6;
  int lane = threadIdx.x & 63;
  int q = lane & 15, g = lane >> 4;
  int qs = q & 7;
  int q0 = ql * 64 + w * 16;
  int b = bh >> 4, h = bh & 15;

  const u16* base = qkv + (size_t)b * F * NQ + h * 192;
  const u16* VtBH = Vt + (size_t)bh * 65536;

  __shared__ u16 S[24576];

  int i8 = lane >> 3;
  int ic = lane & 7;

  const float qscale = 0.125f * 1.4426950408889634f;
  bf16x8 Qf0, Qf1;
  {
    const u16* qp = base + (size_t)(q0 + q) * NQ + g * 8;
    union { int4 v; u16 u[8]; } uu0, uu1;
    uu0.v = *(const int4*)(qp);
    uu1.v = *(const int4*)(qp + 32);
    union { u32 w4[4]; bf16x8 v; } p0, p1;
    #pragma unroll
    for (int j = 0; j < 4; ++j) {
      p0.w4[j] = cvtpk(bf2f(uu0.u[2 * j]) * qscale, bf2f(uu0.u[2 * j + 1]) * qscale);
      p1.w4[j] = cvtpk(bf2f(uu1.u[2 * j]) * qscale, bf2f(uu1.u[2 * j + 1]) * qscale);
    }
    Qf0 = p0.v; Qf1 = p1.v;
  }

  // ones A-fragment for the lsum MFMA
  union { u16 u[8]; bf16x8 v; } ones_;
  #pragma unroll
  for (int j = 0; j < 8; ++j) ones_.u[j] = 0x3F80;
  const bf16x8 Ones = ones_.v;

  f32x4 acc[4] = {};
  f32x4 accS = {};                 // every element accumulates full lsum(q)
  float m = 0.0f;

  #define STAGE(buf, kt)                                                       \
    do {                                                                       \
      int kb_ = (kt) * 64;                                                     \
      _Pragma("unroll")                                                        \
      for (int rr = 0; rr < 2; ++rr) {                                         \
        int r_ = rr * 32 + w * 8 + i8;                                         \
        int sc_ = (ic ^ (r_ & 7)) * 8;                                         \
        const u16* ks_ = base + (size_t)(kb_ + r_) * NQ + 64 + sc_;            \
        const u16* vs_ = VtBH + (size_t)r_ * 1024 + kb_ + sc_;                 \
        __builtin_amdgcn_global_load_lds((gas_ptr)ks_,                         \
            (las_ptr)&S[(buf) * 4096 + (rr * 32 + w * 8) * 64], 16, 0, 0);     \
        __builtin_amdgcn_global_load_lds((gas_ptr)vs_,                         \
            (las_ptr)&S[12288 + (buf) * 4096 + (rr * 32 + w * 8) * 64], 16, 0, 0);\
      }                                                                        \
    } while (0)

  __builtin_amdgcn_sched_barrier(0);
  STAGE(0, 0);
  STAGE(1, 1);
  asm volatile("s_waitcnt vmcnt(4)" ::: "memory");
  __builtin_amdgcn_s_barrier();
  __builtin_amdgcn_sched_barrier(0);

  #pragma unroll
  for (int kt = 0; kt < 16; ++kt) {
    const int cur = kt % 3;
    const int stg = (kt + 2) % 3;
    if (kt < 14) STAGE(stg, kt + 2);

    const u16* Kb = &S[cur * 4096];
    const u16* Vb = &S[12288 + cur * 4096];

    f32x4 s[4];
    f32x4 seed = {-m, -m, -m, -m};
    __builtin_amdgcn_s_setprio(1);
    #pragma unroll
    for (int ks = 0; ks < 4; ++ks) {
      int row = ks * 16 + q;
      int4 k0 = *(const int4*)&Kb[row * 64 + ((g ^ qs) * 8)];
      int4 k1 = *(const int4*)&Kb[row * 64 + (((4 + g) ^ qs) * 8)];
      f32x4 sv = seed;
      sv = __builtin_amdgcn_mfma_f32_16x16x32_bf16(__builtin_bit_cast(bf16x8, k0), Qf0, sv, 0, 0, 0);
      sv = __builtin_amdgcn_mfma_f32_16x16x32_bf16(__builtin_bit_cast(bf16x8, k1), Qf1, sv, 0, 0, 0);
      s[ks] = sv;
    }
    __builtin_amdgcn_s_setprio(0);

    float a0 = fmaxf(fmaxf(s[0][0], s[0][1]), s[0][2]);
    float a1 = fmaxf(fmaxf(s[0][3], s[1][0]), s[1][1]);
    float a2 = fmaxf(fmaxf(s[1][2], s[1][3]), s[2][0]);
    float a3 = fmaxf(fmaxf(s[2][1], s[2][2]), s[2][3]);
    float a4 = fmaxf(fmaxf(s[3][0], s[3][1]), s[3][2]);
    float tmx = fmaxf(fmaxf(fmaxf(a0, a1), a2), fmaxf(fmaxf(a3, a4), s[3][3]));

    float p[16];
    if (__builtin_expect(__any(tmx > 8.0f), 0)) {
      float tr = fmaxf(tmx, __shfl_xor(tmx, 16, 64));
      tr = fmaxf(tr, __shfl_xor(tr, 32, 64));
      float dm = fmaxf(tr, 0.f);
      float alpha = fexp2(-dm);
      acc[0] *= alpha; acc[1] *= alpha; acc[2] *= alpha; acc[3] *= alpha;
      accS *= alpha;
      m += dm;
      #pragma unroll
      for (int ks = 0; ks < 4; ++ks) {
        p[ks * 4 + 0] = fexp2(s[ks][0] - dm);
        p[ks * 4 + 1] = fexp2(s[ks][1] - dm);
        p[ks * 4 + 2] = fexp2(s[ks][2] - dm);
        p[ks * 4 + 3] = fexp2(s[ks][3] - dm);
      }
    } else {
      #pragma unroll
      for (int ks = 0; ks < 4; ++ks) {
        p[ks * 4 + 0] = fexp2(s[ks][0]);
        p[ks * 4 + 1] = fexp2(s[ks][1]);
        p[ks * 4 + 2] = fexp2(s[ks][2]);
        p[ks * 4 + 3] = fexp2(s[ks][3]);
      }
    }

    union { u32 w4[4]; bf16x8 v; } pb0, pb1;
    pb0.w4[0] = cvtpk(p[0], p[1]);   pb0.w4[1] = cvtpk(p[2], p[3]);
    pb0.w4[2] = cvtpk(p[4], p[5]);   pb0.w4[3] = cvtpk(p[6], p[7]);
    pb1.w4[0] = cvtpk(p[8], p[9]);   pb1.w4[1] = cvtpk(p[10], p[11]);
    pb1.w4[2] = cvtpk(p[12], p[13]); pb1.w4[3] = cvtpk(p[14], p[15]);

    __builtin_amdgcn_s_setprio(1);
    #pragma unroll
    for (int dt = 0; dt < 4; ++dt) {
      int row = dt * 16 + q;
      int4 v0 = *(const int4*)&Vb[row * 64 + ((g ^ qs) * 8)];
      int4 v1 = *(const int4*)&Vb[row * 64 + (((4 + g) ^ qs) * 8)];
      acc[dt] = __builtin_amdgcn_mfma_f32_16x16x32_bf16(__builtin_bit_cast(bf16x8, v0), pb0.v, acc[dt], 0, 0, 0);
      acc[dt] = __builtin_amdgcn_mfma_f32_16x16x32_bf16(__builtin_bit_cast(bf16x8, v1), pb1.v, acc[dt], 0, 0, 0);
    }
    // lsum: D[row][q] = sum_k pb[k][q] — every accS element = lsum(q)
    accS = __builtin_amdgcn_mfma_f32_16x16x32_bf16(Ones, pb0.v, accS, 0, 0, 0);
    accS = __builtin_amdgcn_mfma_f32_16x16x32_bf16(Ones, pb1.v, accS, 0, 0, 0);
    __builtin_amdgcn_s_setprio(0);

    if (kt < 14) {
      asm volatile("s_waitcnt vmcnt(4)" ::: "memory");
    } else {
      asm volatile("s_waitcnt vmcnt(0)" ::: "memory");
    }
    __builtin_amdgcn_s_barrier();
    __builtin_amdgcn_sched_barrier(0);
  }
  #undef STAGE

  float inv = 1.0f / accS[0];

  float* oT = (float*)S + (size_t)w * 1088;
  #pragma unroll
  for (int dt = 0; dt < 4; ++dt) {
    oT[(dt * 16 + g * 4 + 0) * 17 + q] = acc[dt][0] * inv;
    oT[(dt * 16 + g * 4 + 1) * 17 + q] = acc[dt][1] * inv;
    oT[(dt * 16 + g * 4 + 2) * 17 + q] = acc[dt][2] * inv;
    oT[(dt * 16 + g * 4 + 3) * 17 + q] = acc[dt][3] * inv;
  }
  asm volatile("s_waitcnt lgkmcnt(0)" ::: "memory");
  int oq = lane >> 2, dc = (lane & 3) * 16;
  float* orow = out + (size_t)(b * F + q0 + oq) * 1024 + h * 64 + dc;
  #pragma unroll
  for (int c4 = 0; c4 < 4; ++c4) {
    float4 v;
    v.x = oT[(dc + c4 * 4 + 0) * 17 + oq];
    v.y = oT[(dc + c4 * 4 + 1) * 17 + oq];
    v.z = oT[(dc + c4 * 4 + 2) * 17 + oq];
    v.w = oT[(dc + c4 * 4 + 3) * 17 + oq];
    *(float4*)(orow + c4 * 4) = v;
  }
}

// ---------------------------------------------------------------------------
extern "C" void kernel_launch(void* const* d_in, const int* in_sizes, int n_in,
                              void* d_out, int out_size, void* d_ws, size_t ws_size,
                              hipStream_t stream) {
  const float* x     = (const float*)d_in[0];
  const float* gamma = (const float*)d_in[1];
  const float* beta  = (const float*)d_in[2];
  const float* W     = (const float*)d_in[3];
  const float* bias  = (const float*)d_in[4];
  float* out = (float*)d_out;

  char* ws = (char*)d_ws;
  u16* xn  = (u16*)ws;                                   // 16 MB
  u16* Wb  = (u16*)(ws + (size_t)16 * 1024 * 1024);      //  6 MB
  u16* qkv = (u16*)(ws + (size_t)22 * 1024 * 1024);      // 48 MB
  u16* Vt  = (u16*)(ws + (size_t)70 * 1024 * 1024);      // 16 MB

  bn_norm_kernel<<<1024, 256, 0, stream>>>(x, gamma, beta, xn);
  wconv_kernel<<<768, 256, 0, stream>>>(W, Wb);
  gemm_qkv_kernel<<<dim3(64, 24), 256, 0, stream>>>(xn, Wb, bias, qkv, Vt);
  attn_kernel<<<2048, 256, 0, stream>>>(qkv, Vt, out);
}

// Round 20
// 137.893 us; speedup vs baseline: 1.0892x; 1.0445x over previous
//
#include <hip/hip_runtime.h>

typedef unsigned short u16;
typedef unsigned int   u32;

typedef __bf16 bf16x8 __attribute__((ext_vector_type(8)));
typedef float  f32x4  __attribute__((ext_vector_type(4)));

typedef const __attribute__((address_space(1))) void* gas_ptr;
typedef __attribute__((address_space(3))) void* las_ptr;

__device__ __forceinline__ u16 f2bf(float f) {
  u32 u = __builtin_bit_cast(u32, f);
  u += 0x7fffu + ((u >> 16) & 1u);
  return (u16)(u >> 16);
}
__device__ __forceinline__ float bf2f(u16 u) {
  return __builtin_bit_cast(float, ((u32)u) << 16);
}
// packed f32->bf16x2 hardware convert (RTNE), 1 VALU op per pair
__device__ __forceinline__ u32 cvtpk(float a, float b) {
  u32 r;
  asm("v_cvt_pk_bf16_f32 %0, %1, %2" : "=v"(r) : "v"(a), "v"(b));
  return r;
}
// raw v_exp_f32 (2^x, ~1ulp)
__device__ __forceinline__ float fexp2(float x) {
  return __builtin_amdgcn_exp2f(x);
}

// ---------------------------------------------------------------------------
// Kernel 1: fused BatchNorm (blocks 0..1023) + W_qkv bf16 convert (1024..1791)
// ---------------------------------------------------------------------------
__global__ __launch_bounds__(256) void prep_kernel(
    const float* __restrict__ x, const float* __restrict__ gamma,
    const float* __restrict__ beta, u16* __restrict__ xn,
    const float* __restrict__ W, u16* __restrict__ Wb) {
  __shared__ float sh[8192];
  __shared__ float ps[4], pq[4], sc[2];
  const int F = 1024, E = 1024;

  if (blockIdx.x >= 1024) {
    // ---- wconv part: grid-stride over 3072x1024 f32 -> bf16
    const int total = 3072 * 1024 / 4;
    for (int i = (blockIdx.x - 1024) * 256 + threadIdx.x; i < total; i += 768 * 256) {
      float4 v = ((const float4*)W)[i];
      ushort4 o;
      o.x = f2bf(v.x); o.y = f2bf(v.y); o.z = f2bf(v.z); o.w = f2bf(v.w);
      ((ushort4*)Wb)[i] = o;
    }
    return;
  }

  // ---- bn part: one block per f
  int f = blockIdx.x;
  const float* xf = x + (size_t)f * E;
  float ls = 0.f, lq = 0.f;
  for (int i = threadIdx.x; i < 8192; i += 256) {
    int b = i >> 10, e = i & 1023;
    float v = xf[(size_t)b * F * E + e];
    sh[i] = v;
    ls += v;
    lq += v * v;
  }
  #pragma unroll
  for (int o = 32; o > 0; o >>= 1) {
    ls += __shfl_down(ls, o, 64);
    lq += __shfl_down(lq, o, 64);
  }
  int w = threadIdx.x >> 6;
  if ((threadIdx.x & 63) == 0) { ps[w] = ls; pq[w] = lq; }
  __syncthreads();
  if (threadIdx.x == 0) {
    float s = ps[0] + ps[1] + ps[2] + ps[3];
    float q = pq[0] + pq[1] + pq[2] + pq[3];
    float mean = s * (1.f / 8192.f);
    float var = q * (1.f / 8192.f) - mean * mean;
    float scale = gamma[f] * rsqrtf(var + 1e-5f);
    sc[0] = scale;
    sc[1] = beta[f] - mean * scale;
  }
  __syncthreads();
  float scale = sc[0], shift = sc[1];
  for (int i = threadIdx.x; i < 8192; i += 256) {
    int b = i >> 10, e = i & 1023;
    xn[((size_t)(b * F + f)) * E + e] = f2bf(sh[i] * scale + shift);
  }
}

// ---------------------------------------------------------------------------
// Kernel 3: GEMM (m97 structure + R15 swizzle) with FUSED V-transpose epilogue
// (R16-verified). Q/K cols -> qkv; V cols -> Vt with baked key permutation.
// ---------------------------------------------------------------------------
__global__ __launch_bounds__(256) void gemm_qkv_kernel(
    const u16* __restrict__ A, const u16* __restrict__ Bw,
    const float* __restrict__ bias, u16* __restrict__ C,
    u16* __restrict__ Vt) {
  const int K = 1024, N = 3072;
  __shared__ u16 As[128 * 32];
  __shared__ u16 Bs[128 * 32];

  int m0 = blockIdx.x * 128, n0 = blockIdx.y * 128;
  int t = threadIdx.x, lane = t & 63, w = t >> 6;
  int wr = w >> 1, wc = w & 1;
  int r = lane & 15, g = lane >> 4;

  int srow = t >> 2;
  int scol = ((t & 3) ^ ((srow >> 1) & 3)) * 8;   // pre-swizzled source chunk
  const u16* gA  = A  + (size_t)(m0 + srow) * K + scol;
  const u16* gA2 = A  + (size_t)(m0 + 64 + srow) * K + scol;
  const u16* gB  = Bw + (size_t)(n0 + srow) * K + scol;
  const u16* gB2 = Bw + (size_t)(n0 + 64 + srow) * K + scol;
  u16* lA  = As + t * 8;
  u16* lA2 = As + 2048 + t * 8;
  u16* lB  = Bs + t * 8;
  u16* lB2 = Bs + 2048 + t * 8;

  f32x4 acc[4][4] = {};

  int rc = (g ^ ((r >> 1) & 3)) * 8;
  const u16* pA = As + (size_t)(wr * 64 + r) * 32 + rc;
  const u16* pB = Bs + (size_t)(wc * 64 + r) * 32 + rc;

  for (int k0 = 0; k0 < K; k0 += 32) {
    __builtin_amdgcn_global_load_lds((gas_ptr)gA,  (las_ptr)lA,  16, 0, 0);
    __builtin_amdgcn_global_load_lds((gas_ptr)gA2, (las_ptr)lA2, 16, 0, 0);
    __builtin_amdgcn_global_load_lds((gas_ptr)gB,  (las_ptr)lB,  16, 0, 0);
    __builtin_amdgcn_global_load_lds((gas_ptr)gB2, (las_ptr)lB2, 16, 0, 0);
    gA += 32; gA2 += 32; gB += 32; gB2 += 32;
    __syncthreads();

    bf16x8 af[4], bfr[4];
    #pragma unroll
    for (int mi = 0; mi < 4; ++mi)
      af[mi] = __builtin_bit_cast(bf16x8, *(const int4*)(pA + mi * 512));
    #pragma unroll
    for (int ni = 0; ni < 4; ++ni)
      bfr[ni] = __builtin_bit_cast(bf16x8, *(const int4*)(pB + ni * 512));
    #pragma unroll
    for (int mi = 0; mi < 4; ++mi)
      #pragma unroll
      for (int ni = 0; ni < 4; ++ni)
        acc[mi][ni] = __builtin_amdgcn_mfma_f32_16x16x32_bf16(af[mi], bfr[ni], acc[mi][ni], 0, 0, 0);
    __syncthreads();
  }

  // ---- epilogue: Q/K -> qkv ; V -> Vt (baked permutation)
  int b_ = m0 >> 10;
  #pragma unroll
  for (int ni = 0; ni < 4; ++ni) {
    int colb = n0 + wc * 64 + ni * 16;        // wave-uniform fragment base
    int col = colb + r;
    float bv = bias[col];
    int h_ = colb / 192;
    int rr = colb - h_ * 192;
    if (rr >= 128) {
      int d_ = rr - 128 + r;
      u16* vtd = Vt + (size_t)(b_ * 16 + h_) * 65536 + (size_t)d_ * 1024;
      #pragma unroll
      for (int mi = 0; mi < 4; ++mi) {
        int fbase = (m0 & 1023) + wr * 64 + mi * 16 + g * 4;
        int pos = (fbase & ~31) + ((g >> 1) * 16) + ((g & 1) * 8) + ((mi & 1) * 4);
        uint2 st;
        st.x = cvtpk(acc[mi][ni][0] + bv, acc[mi][ni][1] + bv);
        st.y = cvtpk(acc[mi][ni][2] + bv, acc[mi][ni][3] + bv);
        *(uint2*)(vtd + pos) = st;
      }
    } else {
      #pragma unroll
      for (int mi = 0; mi < 4; ++mi) {
        int row = m0 + wr * 64 + mi * 16 + g * 4;
        #pragma unroll
        for (int j = 0; j < 4; ++j)
          C[(size_t)(row + j) * N + col] = f2bf(acc[mi][ni][j] + bv);
      }
    }
  }
}

// ---------------------------------------------------------------------------
// Kernel 4: flash attention v12 — v11 math (fexp2, seeded-C, cvt_pk, ones-MFMA
// lsum) on a DOUBLE-buffered 32KB LDS schedule (5 blocks/CU residency).
// ---------------------------------------------------------------------------
__global__ __launch_bounds__(256) void attn_kernel(
    const u16* __restrict__ qkv, const u16* __restrict__ Vt,
    float* __restrict__ out) {
  const int F = 1024, NQ = 3072;
  int bid = blockIdx.x;           // 2048 blocks
  int xcd = bid & 7;
  int li  = bid >> 3;             // 0..255
  int bh  = ((li >> 4) << 3) | xcd;
  int ql  = li & 15;
  int w   = threadIdx.x >> 6;
  int lane = threadIdx.x & 63;
  int q = lane & 15, g = lane >> 4;
  int qs = q & 7;
  int q0 = ql * 64 + w * 16;
  int b = bh >> 4, h = bh & 15;

  const u16* base = qkv + (size_t)b * F * NQ + h * 192;
  const u16* VtBH = Vt + (size_t)bh * 65536;

  // 2 K bufs @ 0/4096, 2 V bufs @ 8192/12288 (u16 units; 32 KB)
  __shared__ u16 S[16384];

  int i8 = lane >> 3;
  int ic = lane & 7;

  const float qscale = 0.125f * 1.4426950408889634f;
  bf16x8 Qf0, Qf1;
  {
    const u16* qp = base + (size_t)(q0 + q) * NQ + g * 8;
    union { int4 v; u16 u[8]; } uu0, uu1;
    uu0.v = *(const int4*)(qp);
    uu1.v = *(const int4*)(qp + 32);
    union { u32 w4[4]; bf16x8 v; } p0, p1;
    #pragma unroll
    for (int j = 0; j < 4; ++j) {
      p0.w4[j] = cvtpk(bf2f(uu0.u[2 * j]) * qscale, bf2f(uu0.u[2 * j + 1]) * qscale);
      p1.w4[j] = cvtpk(bf2f(uu1.u[2 * j]) * qscale, bf2f(uu1.u[2 * j + 1]) * qscale);
    }
    Qf0 = p0.v; Qf1 = p1.v;
  }

  // ones A-fragment for the lsum MFMA
  union { u16 u[8]; bf16x8 v; } ones_;
  #pragma unroll
  for (int j = 0; j < 8; ++j) ones_.u[j] = 0x3F80;
  const bf16x8 Ones = ones_.v;

  f32x4 acc[4] = {};
  f32x4 accS = {};                 // every element accumulates full lsum(q)
  float m = 0.0f;

  #define STAGE(buf, kt)                                                       \
    do {                                                                       \
      int kb_ = (kt) * 64;                                                     \
      _Pragma("unroll")                                                        \
      for (int rr = 0; rr < 2; ++rr) {                                         \
        int r_ = rr * 32 + w * 8 + i8;                                         \
        int sc_ = (ic ^ (r_ & 7)) * 8;                                         \
        const u16* ks_ = base + (size_t)(kb_ + r_) * NQ + 64 + sc_;            \
        const u16* vs_ = VtBH + (size_t)r_ * 1024 + kb_ + sc_;                 \
        __builtin_amdgcn_global_load_lds((gas_ptr)ks_,                         \
            (las_ptr)&S[(buf) * 4096 + (rr * 32 + w * 8) * 64], 16, 0, 0);     \
        __builtin_amdgcn_global_load_lds((gas_ptr)vs_,                         \
            (las_ptr)&S[8192 + (buf) * 4096 + (rr * 32 + w * 8) * 64], 16, 0, 0);\
      }                                                                        \
    } while (0)

  STAGE(0, 0);
  asm volatile("s_waitcnt vmcnt(0)" ::: "memory");
  __builtin_amdgcn_s_barrier();
  __builtin_amdgcn_sched_barrier(0);

  #pragma unroll
  for (int kt = 0; kt < 16; ++kt) {
    const int cur = kt & 1;
    if (kt < 15) STAGE(cur ^ 1, kt + 1);

    const u16* Kb = &S[cur * 4096];
    const u16* Vb = &S[8192 + cur * 4096];

    f32x4 s[4];
    f32x4 seed = {-m, -m, -m, -m};
    __builtin_amdgcn_s_setprio(1);
    #pragma unroll
    for (int ks = 0; ks < 4; ++ks) {
      int row = ks * 16 + q;
      int4 k0 = *(const int4*)&Kb[row * 64 + ((g ^ qs) * 8)];
      int4 k1 = *(const int4*)&Kb[row * 64 + (((4 + g) ^ qs) * 8)];
      f32x4 sv = seed;
      sv = __builtin_amdgcn_mfma_f32_16x16x32_bf16(__builtin_bit_cast(bf16x8, k0), Qf0, sv, 0, 0, 0);
      sv = __builtin_amdgcn_mfma_f32_16x16x32_bf16(__builtin_bit_cast(bf16x8, k1), Qf1, sv, 0, 0, 0);
      s[ks] = sv;
    }
    __builtin_amdgcn_s_setprio(0);

    float a0 = fmaxf(fmaxf(s[0][0], s[0][1]), s[0][2]);
    float a1 = fmaxf(fmaxf(s[0][3], s[1][0]), s[1][1]);
    float a2 = fmaxf(fmaxf(s[1][2], s[1][3]), s[2][0]);
    float a3 = fmaxf(fmaxf(s[2][1], s[2][2]), s[2][3]);
    float a4 = fmaxf(fmaxf(s[3][0], s[3][1]), s[3][2]);
    float tmx = fmaxf(fmaxf(fmaxf(a0, a1), a2), fmaxf(fmaxf(a3, a4), s[3][3]));

    float p[16];
    if (__builtin_expect(__any(tmx > 8.0f), 0)) {
      float tr = fmaxf(tmx, __shfl_xor(tmx, 16, 64));
      tr = fmaxf(tr, __shfl_xor(tr, 32, 64));
      float dm = fmaxf(tr, 0.f);
      float alpha = fexp2(-dm);
      acc[0] *= alpha; acc[1] *= alpha; acc[2] *= alpha; acc[3] *= alpha;
      accS *= alpha;
      m += dm;
      #pragma unroll
      for (int ks = 0; ks < 4; ++ks) {
        p[ks * 4 + 0] = fexp2(s[ks][0] - dm);
        p[ks * 4 + 1] = fexp2(s[ks][1] - dm);
        p[ks * 4 + 2] = fexp2(s[ks][2] - dm);
        p[ks * 4 + 3] = fexp2(s[ks][3] - dm);
      }
    } else {
      #pragma unroll
      for (int ks = 0; ks < 4; ++ks) {
        p[ks * 4 + 0] = fexp2(s[ks][0]);
        p[ks * 4 + 1] = fexp2(s[ks][1]);
        p[ks * 4 + 2] = fexp2(s[ks][2]);
        p[ks * 4 + 3] = fexp2(s[ks][3]);
      }
    }

    union { u32 w4[4]; bf16x8 v; } pb0, pb1;
    pb0.w4[0] = cvtpk(p[0], p[1]);   pb0.w4[1] = cvtpk(p[2], p[3]);
    pb0.w4[2] = cvtpk(p[4], p[5]);   pb0.w4[3] = cvtpk(p[6], p[7]);
    pb1.w4[0] = cvtpk(p[8], p[9]);   pb1.w4[1] = cvtpk(p[10], p[11]);
    pb1.w4[2] = cvtpk(p[12], p[13]); pb1.w4[3] = cvtpk(p[14], p[15]);

    __builtin_amdgcn_s_setprio(1);
    #pragma unroll
    for (int dt = 0; dt < 4; ++dt) {
      int row = dt * 16 + q;
      int4 v0 = *(const int4*)&Vb[row * 64 + ((g ^ qs) * 8)];
      int4 v1 = *(const int4*)&Vb[row * 64 + (((4 + g) ^ qs) * 8)];
      acc[dt] = __builtin_amdgcn_mfma_f32_16x16x32_bf16(__builtin_bit_cast(bf16x8, v0), pb0.v, acc[dt], 0, 0, 0);
      acc[dt] = __builtin_amdgcn_mfma_f32_16x16x32_bf16(__builtin_bit_cast(bf16x8, v1), pb1.v, acc[dt], 0, 0, 0);
    }
    // lsum: every accS element accumulates the full row-sum of P
    accS = __builtin_amdgcn_mfma_f32_16x16x32_bf16(Ones, pb0.v, accS, 0, 0, 0);
    accS = __builtin_amdgcn_mfma_f32_16x16x32_bf16(Ones, pb1.v, accS, 0, 0, 0);
    __builtin_amdgcn_s_setprio(0);

    asm volatile("s_waitcnt vmcnt(0)" ::: "memory");
    __builtin_amdgcn_s_barrier();
    __builtin_amdgcn_sched_barrier(0);
  }
  #undef STAGE

  float inv = 1.0f / accS[0];

  float* oT = (float*)S + (size_t)w * 1088;   // 4 x 4352B = 17408B < 32KB
  #pragma unroll
  for (int dt = 0; dt < 4; ++dt) {
    oT[(dt * 16 + g * 4 + 0) * 17 + q] = acc[dt][0] * inv;
    oT[(dt * 16 + g * 4 + 1) * 17 + q] = acc[dt][1] * inv;
    oT[(dt * 16 + g * 4 + 2) * 17 + q] = acc[dt][2] * inv;
    oT[(dt * 16 + g * 4 + 3) * 17 + q] = acc[dt][3] * inv;
  }
  asm volatile("s_waitcnt lgkmcnt(0)" ::: "memory");
  int oq = lane >> 2, dc = (lane & 3) * 16;
  float* orow = out + (size_t)(b * F + q0 + oq) * 1024 + h * 64 + dc;
  #pragma unroll
  for (int c4 = 0; c4 < 4; ++c4) {
    float4 v;
    v.x = oT[(dc + c4 * 4 + 0) * 17 + oq];
    v.y = oT[(dc + c4 * 4 + 1) * 17 + oq];
    v.z = oT[(dc + c4 * 4 + 2) * 17 + oq];
    v.w = oT[(dc + c4 * 4 + 3) * 17 + oq];
    *(float4*)(orow + c4 * 4) = v;
  }
}

// ---------------------------------------------------------------------------
extern "C" void kernel_launch(void* const* d_in, const int* in_sizes, int n_in,
                              void* d_out, int out_size, void* d_ws, size_t ws_size,
                              hipStream_t stream) {
  const float* x     = (const float*)d_in[0];
  const float* gamma = (const float*)d_in[1];
  const float* beta  = (const float*)d_in[2];
  const float* W     = (const float*)d_in[3];
  const float* bias  = (const float*)d_in[4];
  float* out = (float*)d_out;

  char* ws = (char*)d_ws;
  u16* xn  = (u16*)ws;                                   // 16 MB
  u16* Wb  = (u16*)(ws + (size_t)16 * 1024 * 1024);      //  6 MB
  u16* qkv = (u16*)(ws + (size_t)22 * 1024 * 1024);      // 48 MB
  u16* Vt  = (u16*)(ws + (size_t)70 * 1024 * 1024);      // 16 MB

  prep_kernel<<<1792, 256, 0, stream>>>(x, gamma, beta, xn, W, Wb);
  gemm_qkv_kernel<<<dim3(64, 24), 256, 0, stream>>>(xn, Wb, bias, qkv, Vt);
  attn_kernel<<<2048, 256, 0, stream>>>(qkv, Vt, out);
}